// Round 10
// baseline (199.831 us; speedup 1.0000x reference)
//
#include <hip/hip_runtime.h>
#include <hip/hip_bf16.h>

static constexpr int HEADS = 4;
static constexpr int HID   = 64;
static constexpr int HC    = 256;   // HEADS*HID
static constexpr int NCLS  = 10;

typedef short    bf16x8 __attribute__((ext_vector_type(8)));
typedef _Float16 f16x8  __attribute__((ext_vector_type(8)));
typedef _Float16 f16x4  __attribute__((ext_vector_type(4)));
typedef _Float16 f16x2  __attribute__((ext_vector_type(2)));
typedef float    f32x4  __attribute__((ext_vector_type(4)));

__device__ inline unsigned short f2bf(float f) {
    union { float f; unsigned u; } c; c.f = f;
    unsigned r = (c.u + 0x7fff + ((c.u >> 16) & 1)) >> 16;  // RNE
    return (unsigned short)r;
}
__device__ inline unsigned short f2h(float f) {
    _Float16 h = (_Float16)f; unsigned short u; __builtin_memcpy(&u, &h, 2); return u;
}
__device__ inline float h2f(unsigned short u) {
    _Float16 h; __builtin_memcpy(&h, &u, 2); return (float)h;
}
__device__ inline f16x2 u2h2(unsigned u) {
    union { unsigned u; f16x2 h; } c; c.u = u; return c.h;
}

// attn (dup f16 pair) x gathered channels -> packed f16 accumulate
__device__ inline void edge_acc(unsigned aw, f16x4 X, f16x2& a0, f16x2& a1) {
    f16x2 a  = u2h2(aw);
    f16x2 lo = __builtin_shufflevector(X, X, 0, 1);
    f16x2 hi = __builtin_shufflevector(X, X, 2, 3);
    a0 = a * lo + a0;   // v_pk_fma_f16
    a1 = a * hi + a1;
}

// ------------------------------------------------------------------ prep ----
// b=0: cE; b=1..256: Wt; b=257..272: fcWh; b>=273: zero deg (fused memset)
__global__ void prep_kernel(const float* __restrict__ We, const float* __restrict__ attE,
                            float* __restrict__ cE, const float* __restrict__ W,
                            unsigned short* __restrict__ Wt, const float* __restrict__ fcW,
                            unsigned short* __restrict__ fcWh, int* __restrict__ deg,
                            int Nn) {
    int b = blockIdx.x, t = threadIdx.x;
    if (b == 0) {
        float p = We[t] * attE[t];
#pragma unroll
        for (int d = 32; d; d >>= 1) p += __shfl_xor(p, d, 64);
        if ((t & 63) == 0) cE[t >> 6] = p;
    } else if (b <= 256) {
        int k = b - 1;
        Wt[t * 256 + k] = f2bf(W[k * 256 + t]);
    } else if (b <= 272) {
        int j = b - 257;               // 0..15
        unsigned short v = 0;
        if (j < NCLS) v = f2h(fcW[t * NCLS + j]);
        fcWh[j * 256 + t] = v;
    } else {
        int i = (b - 273) * 256 + t;
        if (i < Nn) deg[i] = 0;
    }
}

// ------------------------------------------------------------ MFMA GEMM -----
// XHh[M,256](f16) = X[M,256](f32) @ Wt^T (bf16 MFMA).
__global__ __launch_bounds__(256) void gemm_mfma(const float* __restrict__ X,
                                                 const unsigned short* __restrict__ Bt,
                                                 unsigned short* __restrict__ XHh, int M) {
    __shared__ alignas(16) unsigned short As[128][40];
    __shared__ alignas(16) unsigned short Bs[128][40];  // Bs[col][k]
    const int tid = threadIdx.x;
    const int lane = tid & 63, wid = tid >> 6;
    const int wr = wid >> 1, wc = wid & 1;
    const int bm = blockIdx.x * 128, bn = blockIdx.y * 128;
    const int fr = lane & 15, kg = lane >> 4;

    f32x4 acc[4][4] = {};

    for (int k0 = 0; k0 < 256; k0 += 32) {
        __syncthreads();
#pragma unroll
        for (int ss = 0; ss < 4; ++ss) {
            int idx = tid + (ss << 8);
            int row = idx >> 3, seg = idx & 7;
            int grow = bm + row;
            float4 av = make_float4(0.f, 0.f, 0.f, 0.f);
            if (grow < M) av = *(const float4*)&X[(size_t)grow * 256 + k0 + seg * 4];
            ushort4 ab = make_ushort4(f2bf(av.x), f2bf(av.y), f2bf(av.z), f2bf(av.w));
            *(ushort4*)&As[row][seg * 4] = ab;
        }
#pragma unroll
        for (int qq = 0; qq < 2; ++qq) {
            int q = tid + (qq << 8);
            int row = q >> 2, part = q & 3;
            const ushort4* bp = (const ushort4*)&Bt[(size_t)(bn + row) * 256 + k0 + part * 8];
            *(ushort4*)&Bs[row][part * 8]     = bp[0];
            *(ushort4*)&Bs[row][part * 8 + 4] = bp[1];
        }
        __syncthreads();

        bf16x8 af[4], bf[4];
#pragma unroll
        for (int i = 0; i < 4; ++i)
            af[i] = *(const bf16x8*)&As[wr * 64 + i * 16 + fr][kg * 8];
#pragma unroll
        for (int j = 0; j < 4; ++j)
            bf[j] = *(const bf16x8*)&Bs[wc * 64 + j * 16 + fr][kg * 8];
#pragma unroll
        for (int i = 0; i < 4; ++i)
#pragma unroll
            for (int j = 0; j < 4; ++j)
                acc[i][j] = __builtin_amdgcn_mfma_f32_16x16x32_bf16(af[i], bf[j], acc[i][j], 0, 0, 0);
    }

    // C/D layout: col = lane&15, row = (lane>>4)*4 + reg
#pragma unroll
    for (int i = 0; i < 4; ++i) {
#pragma unroll
        for (int j = 0; j < 4; ++j) {
            int col = bn + wc * 64 + j * 16 + fr;
#pragma unroll
            for (int r = 0; r < 4; ++r) {
                int row = bm + wr * 64 + i * 16 + kg * 4 + r;
                if (row < M) XHh[(size_t)row * 256 + col] = f2h(acc[i][j][r]);
            }
        }
    }
}

// ------------------------------------------------------- a_src / a_dst ------
__global__ __launch_bounds__(256) void attn_coef(const unsigned short* __restrict__ xhh,
                                                 const float* __restrict__ attS,
                                                 const float* __restrict__ attD,
                                                 float* __restrict__ a_src,
                                                 float* __restrict__ a_dst,
                                                 int Nn) {
    int wid = threadIdx.x >> 6, lane = threadIdx.x & 63;
    int n = blockIdx.x * 4 + wid;
    if (n >= Nn) return;
    ushort4 xv = *(const ushort4*)&xhh[(size_t)n * HC + lane * 4];
    float x0 = h2f(xv.x), x1 = h2f(xv.y), x2 = h2f(xv.z), x3 = h2f(xv.w);
    float4 sv = *(const float4*)&attS[lane * 4];
    float4 dv = *(const float4*)&attD[lane * 4];
    float ps = x0 * sv.x + x1 * sv.y + x2 * sv.z + x3 * sv.w;
    float pd = x0 * dv.x + x1 * dv.y + x2 * dv.z + x3 * dv.w;
#pragma unroll
    for (int d = 1; d < 16; d <<= 1) {
        ps += __shfl_xor(ps, d, 64);
        pd += __shfl_xor(pd, d, 64);
    }
    if ((lane & 15) == 0) {
        a_src[n * 4 + (lane >> 4)] = ps;
        a_dst[n * 4 + (lane >> 4)] = pd;
    }
}

// ------------------------------------------------------------- CSR build ----
__global__ void hist_kernel(const int* __restrict__ dst, int* __restrict__ deg,
                            int* __restrict__ rank, int E) {
    int e = blockIdx.x * 256 + threadIdx.x;
    if (e < E) rank[e] = atomicAdd(&deg[dst[e]], 1);
}

// scan of PADDED degrees (each deg rounded up to x4)
__global__ __launch_bounds__(1024) void scan1(const int* __restrict__ deg,
                                              int* __restrict__ row_start,
                                              int* __restrict__ bsum, int n) {
    __shared__ int wsum[16];
    const int tid = threadIdx.x, lane = tid & 63, wid = tid >> 6;
    int i = blockIdx.x * 1024 + tid;
    int v = (i < n) ? ((deg[i] + 3) & ~3) : 0;
    int incl = v;
#pragma unroll
    for (int d = 1; d < 64; d <<= 1) {
        int t = __shfl_up(incl, d, 64);
        if (lane >= d) incl += t;
    }
    if (lane == 63) wsum[wid] = incl;
    __syncthreads();
    if (tid < 16) {
        int w = wsum[tid];
#pragma unroll
        for (int d = 1; d < 16; d <<= 1) {
            int t = __shfl_up(w, d, 16);
            if (tid >= d) w += t;
        }
        wsum[tid] = w;
    }
    __syncthreads();
    int waveoff = wid ? wsum[wid - 1] : 0;
    if (i < n) row_start[i] = waveoff + incl - v;
    if (tid == 1023) bsum[blockIdx.x] = waveoff + incl;
}

// fused scan2+scan3
__global__ __launch_bounds__(1024) void scan23(int* __restrict__ row_start,
                                               const int* __restrict__ bsum, int n, int nb) {
    __shared__ int pref[64];
    const int tid = threadIdx.x;
    if (tid < 64) {
        int v = (tid < nb) ? bsum[tid] : 0;
#pragma unroll
        for (int d = 1; d < 64; d <<= 1) {
            int t = __shfl_up(v, d, 64);
            if (tid >= d) v += t;
        }
        pref[tid] = v;
    }
    __syncthreads();
    int add = blockIdx.x ? pref[blockIdx.x - 1] : 0;
    int i = blockIdx.x * 1024 + tid;
    if (i < n) row_start[i] += add;
    if (i == n) row_start[n] = pref[nb - 1];
}

// ------------------------------------------------------------ scatter -------
// Single 8B combined record per edge -> ONE cacheline touch per edge.
__global__ void scatter_sw(const int* __restrict__ src, const int* __restrict__ dst,
                           const float* __restrict__ ew,
                           const int* __restrict__ row_start, const int* __restrict__ rank,
                           int2* __restrict__ sew, int E) {
    int e = blockIdx.x * 256 + threadIdx.x;
    if (e >= E) return;
    int pos = row_start[dst[e]] + rank[e];
    sew[pos] = make_int2(src[e], __float_as_int(ew[e]));
}

// --------------------------------------------------------------- p_pass -----
// One wave per node, 2 passes. Pass1: esum per (node,head). Pass2: write
// NORMALIZED attn = exp(lrelu(alpha))/esum as DUPLICATED f16 pair (one dword
// per slot/head), plus srcs; pads written as 0 (no upstream zeroing needed).
__global__ __launch_bounds__(256) void p_pass(
    const int* __restrict__ row_start, const int* __restrict__ deg,
    const int2* __restrict__ sew, const float* __restrict__ a_src,
    const float* __restrict__ a_dst, const float* __restrict__ cE,
    int* __restrict__ srcs, unsigned* __restrict__ pq, int Nn) {
    const int wid = threadIdx.x >> 6, lane = threadIdx.x & 63;
    const int n = blockIdx.x * 4 + wid;
    if (n >= Nn) return;
    const int rs = row_start[n];
    const int dn = deg[n];
    const int pd = (dn + 3) & ~3;
    const int slot0 = lane >> 2, h = lane & 3;
    const float adn = a_dst[n * 4 + h];
    const float ceh = cE[h];

    float esum = 0.f;
    for (int s = slot0; s < dn; s += 16) {
        int2 r = sew[rs + s];
        float a = a_src[r.x * 4 + h] + adn + ceh * __int_as_float(r.y);
        a = fmaxf(a, 0.2f * a);
        esum += __expf(a);
    }
#pragma unroll
    for (int d = 4; d < 64; d <<= 1) esum += __shfl_xor(esum, d, 64);
    float rin = 1.f / (esum + 1e-16f);

    for (int s = slot0; s < pd; s += 16) {
        int pos = rs + s;
        float at = 0.f;
        int sv = 0;
        if (s < dn) {
            int2 r = sew[pos];                 // L1-hot (pass1 read it)
            sv = r.x;
            float a = a_src[r.x * 4 + h] + adn + ceh * __int_as_float(r.y);
            a = fmaxf(a, 0.2f * a);
            at = __expf(a) * rin;
        }
        if (h == 0) srcs[pos] = sv;
        unsigned ah = f2h(at);
        pq[(size_t)(pos >> 2) * 16 + h * 4 + (pos & 3)] = ah | (ah << 16);
    }
}

// ------------------------------------------------------------- main GAT -----
// One WAVE per node. Lane l owns channels 4l..4l+3 (head myh=l>>4).
// attn pre-normalized -> compute = 2 v_pk_fma_f16 per edge, no psum/div.
// Zero-copy period-4 pipeline: 4 meta slots, 2 gather sets (A,B), unroll-4
// body + guarded static drain. Gathers: SGPR row base (readfirstlane) +
// loop-invariant lane voffset. All chunks full (pads attn=0, src=0).
__global__ __launch_bounds__(256) void gat_main(
    const unsigned short* __restrict__ xhh, const int* __restrict__ row_start,
    const int* __restrict__ srcs, const unsigned* __restrict__ pqw,
    const float* __restrict__ bias, const float* __restrict__ gamma,
    const float* __restrict__ beta, unsigned short* __restrict__ yh, int Nn) {
    const int lane = threadIdx.x & 63, wid = threadIdx.x >> 6;
    const int n = blockIdx.x * 4 + wid;
    if (n >= Nn) return;
    const int myh = lane >> 4;
    const int rs = row_start[n], re = row_start[n + 1];
    const int rs4 = rs >> 2;
    const int G = (re - rs) >> 2;          // all chunks full

    f16x2 acc0 = {(_Float16)0, (_Float16)0};
    f16x2 acc1 = {(_Float16)0, (_Float16)0};

    int4  ms0 = {}, ms1 = {}, ms2 = {}, ms3 = {};
    uint4 mp0 = {}, mp1 = {}, mp2 = {}, mp3 = {};
    f16x4 A0 = {}, A1 = {}, A2 = {}, A3 = {};
    f16x4 B0 = {}, B1 = {}, B2 = {}, B3 = {};

#define META(i, c_) do {                                                       \
    ms##i = *(const int4*)(srcs + ((size_t)(rs4 + (c_)) << 2));                \
    mp##i = *(const uint4*)(pqw + ((size_t)(rs4 + (c_)) << 4) + (myh << 2));   \
} while (0)
#define ROW(D, sv_) do {                                                       \
    unsigned sb_ = __builtin_amdgcn_readfirstlane((unsigned)(sv_));            \
    const f16x4* rp_ = (const f16x4*)(xhh + (size_t)sb_ * HC);                 \
    D = rp_[lane];                                                             \
} while (0)
#define GATH(S, i) do {                                                        \
    ROW(S##0, ms##i.x); ROW(S##1, ms##i.y);                                    \
    ROW(S##2, ms##i.z); ROW(S##3, ms##i.w);                                    \
} while (0)
#define COMP(S, i) do {                                                        \
    edge_acc(mp##i.x, S##0, acc0, acc1);                                       \
    edge_acc(mp##i.y, S##1, acc0, acc1);                                       \
    edge_acc(mp##i.z, S##2, acc0, acc1);                                       \
    edge_acc(mp##i.w, S##3, acc0, acc1);                                       \
} while (0)

    if (G > 0) {
        META(0, 0); GATH(A, 0);
        if (G > 1) { META(1, 1); GATH(B, 1); }
        if (G > 2) META(2, 2);
        if (G > 3) META(3, 3);
        int c = 0;
        for (; c + 8 <= G; c += 4) {
            COMP(A, 0); GATH(A, 2); META(0, c + 4);
            COMP(B, 1); GATH(B, 3); META(1, c + 5);
            COMP(A, 2); GATH(A, 0); META(2, c + 6);
            COMP(B, 3); GATH(B, 1); META(3, c + 7);
        }
        int R = G - c;                      // 1..7
        COMP(A, 0);
        if (c + 2 < G) GATH(A, 2);
        if (c + 4 < G) META(0, c + 4);
        if (R > 1) {
            COMP(B, 1);
            if (c + 3 < G) GATH(B, 3);
            if (c + 5 < G) META(1, c + 5);
            if (R > 2) {
                COMP(A, 2);
                if (c + 4 < G) GATH(A, 0);
                if (c + 6 < G) META(2, c + 6);
                if (R > 3) {
                    COMP(B, 3);
                    if (c + 5 < G) GATH(B, 1);
                    if (R > 4) {
                        COMP(A, 0);
                        if (c + 6 < G) GATH(A, 2);
                        if (R > 5) {
                            COMP(B, 1);
                            if (R > 6) COMP(A, 2);
                        }
                    }
                }
            }
        }
    }
#undef META
#undef ROW
#undef GATH
#undef COMP

    // unpack (attn was pre-normalized; no division)
    float4 bv = *(const float4*)&bias[lane * 4];
    float v0 = (float)acc0[0] + bv.x;
    float v1 = (float)acc0[1] + bv.y;
    float v2 = (float)acc1[0] + bv.z;
    float v3 = (float)acc1[1] + bv.w;

    // LayerNorm over 256 channels (wave-wide reduce)
    float s1 = v0 + v1 + v2 + v3;
    float s2v = v0 * v0 + v1 * v1 + v2 * v2 + v3 * v3;
#pragma unroll
    for (int d = 1; d < 64; d <<= 1) {
        s1 += __shfl_xor(s1, d, 64);
        s2v += __shfl_xor(s2v, d, 64);
    }
    float mu = s1 * (1.f / 256.f);
    float var = s2v * (1.f / 256.f) - mu * mu;
    float rstd = rsqrtf(var + 1e-5f);
    float4 gv = *(const float4*)&gamma[lane * 4];
    float4 btv = *(const float4*)&beta[lane * 4];
    float y0 = fmaxf((v0 - mu) * rstd * gv.x + btv.x, 0.f);
    float y1 = fmaxf((v1 - mu) * rstd * gv.y + btv.y, 0.f);
    float y2 = fmaxf((v2 - mu) * rstd * gv.z + btv.z, 0.f);
    float y3 = fmaxf((v3 - mu) * rstd * gv.w + btv.w, 0.f);

    f16x4 yv;
    yv[0] = (_Float16)y0; yv[1] = (_Float16)y1;
    yv[2] = (_Float16)y2; yv[3] = (_Float16)y3;
    *(f16x4*)&yh[(size_t)n * HC + lane * 4] = yv;
}

// ------------------------------------------------------------ FC (MFMA) -----
// out[M,10] = y[M,256](f16) @ fcWh^T(f16,[16][256]) + fcb. 4 waves x 64 rows.
__global__ __launch_bounds__(256) void fc_gemm(const unsigned short* __restrict__ yh,
                                               const unsigned short* __restrict__ fcWh,
                                               const float* __restrict__ fcb,
                                               float* __restrict__ out, int M) {
    const int lane = threadIdx.x & 63, wid = threadIdx.x >> 6;
    const int rowbase = blockIdx.x * 256 + wid * 64;
    const int fr = lane & 15, kg = lane >> 4;
    f32x4 acc[4] = {};
#pragma unroll
    for (int k0 = 0; k0 < 256; k0 += 32) {
        f16x8 bfr = *(const f16x8*)&fcWh[fr * 256 + k0 + kg * 8];
#pragma unroll
        for (int i = 0; i < 4; ++i) {
            int row = rowbase + i * 16 + fr;
            f16x8 afr = {};
            if (row < M) afr = *(const f16x8*)&yh[(size_t)row * 256 + k0 + kg * 8];
            acc[i] = __builtin_amdgcn_mfma_f32_16x16x32_f16(afr, bfr, acc[i], 0, 0, 0);
        }
    }
    if (fr < NCLS) {
        float bb = fcb[fr];
#pragma unroll
        for (int i = 0; i < 4; ++i) {
#pragma unroll
            for (int r = 0; r < 4; ++r) {
                int row = rowbase + i * 16 + kg * 4 + r;
                if (row < M) out[(size_t)row * NCLS + fr] = acc[i][r] + bb;
            }
        }
    }
}

// ---------------------------------------------------------------- launch ----
extern "C" void kernel_launch(void* const* d_in, const int* in_sizes, int n_in,
                              void* d_out, int out_size, void* d_ws, size_t ws_size,
                              hipStream_t stream) {
    const float* x    = (const float*)d_in[0];
    const int*   ei   = (const int*)d_in[1];
    const float* ew   = (const float*)d_in[2];
    const float* W    = (const float*)d_in[3];
    const float* attS = (const float*)d_in[4];
    const float* attD = (const float*)d_in[5];
    const float* attE = (const float*)d_in[6];
    const float* We   = (const float*)d_in[7];
    const float* bias = (const float*)d_in[8];
    const float* gam  = (const float*)d_in[9];
    const float* bet  = (const float*)d_in[10];
    const float* fcW  = (const float*)d_in[11];
    const float* fcb  = (const float*)d_in[12];
    float* out = (float*)d_out;

    const int Nn = in_sizes[0] / HC;       // 50000
    const int E  = in_sizes[1] / 2;        // 800000
    const int* src = ei;
    const int* dst = ei + E;
    const int nb = (Nn + 1023) / 1024;     // 49
    const int EpMax = E + 4 * Nn;          // worst-case padded slots (x4 pad)

    char* ws = (char*)d_ws;
    size_t off = 0;
    auto alloc = [&](size_t bytes) { void* p = ws + off; off = (off + bytes + 255) & ~size_t(255); return p; };
    unsigned short* xhh  = (unsigned short*)alloc((size_t)Nn * HC * 2);
    unsigned short* yh   = (unsigned short*)alloc((size_t)Nn * HC * 2);
    unsigned short* wt   = (unsigned short*)alloc((size_t)HC * HC * 2);
    unsigned short* fcWh = (unsigned short*)alloc((size_t)16 * HC * 2);
    float* a_srcb    = (float*)alloc((size_t)Nn * 4 * 4);
    float* a_dstb    = (float*)alloc((size_t)Nn * 4 * 4);
    float* cE        = (float*)alloc(256);
    int*   row_start = (int*)  alloc((size_t)(Nn + 1) * 4);
    int*   deg       = (int*)  alloc((size_t)Nn * 4);
    int*   bsum      = (int*)  alloc((size_t)nb * 4);
    int*   rank      = (int*)  alloc((size_t)E * 4);
    int2*  sew       = (int2*) alloc((size_t)EpMax * 8 + 256);   // {src, ew}
    int*   srcs      = (int*)  alloc((size_t)EpMax * 4 + 256);   // +slack
    unsigned* pq     = (unsigned*)alloc((size_t)EpMax * 16 + 1024); // [group][h][4] dup-f16
    (void)ws_size;

    prep_kernel<<<273 + (Nn + 255) / 256, 256, 0, stream>>>(We, attE, cE, W, wt,
                                                            fcW, fcWh, deg, Nn);

    dim3 g((Nn + 127) / 128, 2);
    gemm_mfma<<<g, 256, 0, stream>>>(x, wt, xhh, Nn);

    attn_coef<<<(Nn + 3) / 4, 256, 0, stream>>>(xhh, attS, attD, a_srcb, a_dstb, Nn);
    hist_kernel<<<(E + 255) / 256, 256, 0, stream>>>(dst, deg, rank, E);
    scan1<<<nb, 1024, 0, stream>>>(deg, row_start, bsum, Nn);
    scan23<<<nb, 1024, 0, stream>>>(row_start, bsum, Nn, nb);
    scatter_sw<<<(E + 255) / 256, 256, 0, stream>>>(src, dst, ew, row_start, rank,
                                                    sew, E);
    p_pass<<<(Nn + 3) / 4, 256, 0, stream>>>(row_start, deg, sew,
                                             a_srcb, a_dstb, cE, srcs, pq, Nn);
    gat_main<<<(Nn + 3) / 4, 256, 0, stream>>>(xhh, row_start, srcs, pq,
                                               bias, gam, bet, yh, Nn);
    fc_gemm<<<(Nn + 255) / 256, 256, 0, stream>>>(yh, fcWh, fcb, out, Nn);
}

// Round 12
// 196.734 us; speedup vs baseline: 1.0157x; 1.0157x over previous
//
#include <hip/hip_runtime.h>
#include <hip/hip_bf16.h>

static constexpr int HEADS = 4;
static constexpr int HID   = 64;
static constexpr int HC    = 256;   // HEADS*HID
static constexpr int NCLS  = 10;

typedef short    bf16x8 __attribute__((ext_vector_type(8)));
typedef _Float16 f16x8  __attribute__((ext_vector_type(8)));
typedef _Float16 f16x4  __attribute__((ext_vector_type(4)));
typedef _Float16 f16x2  __attribute__((ext_vector_type(2)));
typedef float    f32x4  __attribute__((ext_vector_type(4)));

__device__ inline unsigned short f2bf(float f) {
    union { float f; unsigned u; } c; c.f = f;
    unsigned r = (c.u + 0x7fff + ((c.u >> 16) & 1)) >> 16;  // RNE
    return (unsigned short)r;
}
__device__ inline unsigned short f2h(float f) {
    _Float16 h = (_Float16)f; unsigned short u; __builtin_memcpy(&u, &h, 2); return u;
}
__device__ inline float h2f(unsigned short u) {
    _Float16 h; __builtin_memcpy(&h, &u, 2); return (float)h;
}

// p (unnormalized, f32) -> attn = p*rin, packed-f16 dup, 2x v_pk_fma_f16
__device__ inline void edge_acc(float p, float rin, f16x4 X, f16x2& a0, f16x2& a1) {
    float a = p * rin;
    auto pk = __builtin_amdgcn_cvt_pkrtz(a, a);   // __fp16 ext_vector(2)
    f16x2 ap;
    __builtin_memcpy(&ap, &pk, sizeof(ap));       // bit-cast to _Float16x2
    f16x2 lo = __builtin_shufflevector(X, X, 0, 1);
    f16x2 hi = __builtin_shufflevector(X, X, 2, 3);
    a0 = ap * lo + a0;   // v_pk_fma_f16
    a1 = ap * hi + a1;
}

// ------------------------------------------------------------------ prep ----
// b=0: cE; b=1..256: Wt; b=257..272: fcWh; b>=273: zero deg (fused memset)
__global__ void prep_kernel(const float* __restrict__ We, const float* __restrict__ attE,
                            float* __restrict__ cE, const float* __restrict__ W,
                            unsigned short* __restrict__ Wt, const float* __restrict__ fcW,
                            unsigned short* __restrict__ fcWh, int* __restrict__ deg,
                            int Nn) {
    int b = blockIdx.x, t = threadIdx.x;
    if (b == 0) {
        float p = We[t] * attE[t];
#pragma unroll
        for (int d = 32; d; d >>= 1) p += __shfl_xor(p, d, 64);
        if ((t & 63) == 0) cE[t >> 6] = p;
    } else if (b <= 256) {
        int k = b - 1;
        Wt[t * 256 + k] = f2bf(W[k * 256 + t]);
    } else if (b <= 272) {
        int j = b - 257;               // 0..15
        unsigned short v = 0;
        if (j < NCLS) v = f2h(fcW[t * NCLS + j]);
        fcWh[j * 256 + t] = v;
    } else {
        int i = (b - 273) * 256 + t;
        if (i < Nn) deg[i] = 0;
    }
}

// ------------------------------------------------------------ MFMA GEMM -----
// XHh[M,256](f16) = X[M,256](f32) @ Wt^T (bf16 MFMA).
__global__ __launch_bounds__(256) void gemm_mfma(const float* __restrict__ X,
                                                 const unsigned short* __restrict__ Bt,
                                                 unsigned short* __restrict__ XHh, int M) {
    __shared__ alignas(16) unsigned short As[128][40];
    __shared__ alignas(16) unsigned short Bs[128][40];  // Bs[col][k]
    const int tid = threadIdx.x;
    const int lane = tid & 63, wid = tid >> 6;
    const int wr = wid >> 1, wc = wid & 1;
    const int bm = blockIdx.x * 128, bn = blockIdx.y * 128;
    const int fr = lane & 15, kg = lane >> 4;

    f32x4 acc[4][4] = {};

    for (int k0 = 0; k0 < 256; k0 += 32) {
        __syncthreads();
#pragma unroll
        for (int ss = 0; ss < 4; ++ss) {
            int idx = tid + (ss << 8);
            int row = idx >> 3, seg = idx & 7;
            int grow = bm + row;
            float4 av = make_float4(0.f, 0.f, 0.f, 0.f);
            if (grow < M) av = *(const float4*)&X[(size_t)grow * 256 + k0 + seg * 4];
            ushort4 ab = make_ushort4(f2bf(av.x), f2bf(av.y), f2bf(av.z), f2bf(av.w));
            *(ushort4*)&As[row][seg * 4] = ab;
        }
#pragma unroll
        for (int qq = 0; qq < 2; ++qq) {
            int q = tid + (qq << 8);
            int row = q >> 2, part = q & 3;
            const ushort4* bp = (const ushort4*)&Bt[(size_t)(bn + row) * 256 + k0 + part * 8];
            *(ushort4*)&Bs[row][part * 8]     = bp[0];
            *(ushort4*)&Bs[row][part * 8 + 4] = bp[1];
        }
        __syncthreads();

        bf16x8 af[4], bf[4];
#pragma unroll
        for (int i = 0; i < 4; ++i)
            af[i] = *(const bf16x8*)&As[wr * 64 + i * 16 + fr][kg * 8];
#pragma unroll
        for (int j = 0; j < 4; ++j)
            bf[j] = *(const bf16x8*)&Bs[wc * 64 + j * 16 + fr][kg * 8];
#pragma unroll
        for (int i = 0; i < 4; ++i)
#pragma unroll
            for (int j = 0; j < 4; ++j)
                acc[i][j] = __builtin_amdgcn_mfma_f32_16x16x32_bf16(af[i], bf[j], acc[i][j], 0, 0, 0);
    }

    // C/D layout: col = lane&15, row = (lane>>4)*4 + reg
#pragma unroll
    for (int i = 0; i < 4; ++i) {
#pragma unroll
        for (int j = 0; j < 4; ++j) {
            int col = bn + wc * 64 + j * 16 + fr;
#pragma unroll
            for (int r = 0; r < 4; ++r) {
                int row = bm + wr * 64 + i * 16 + kg * 4 + r;
                if (row < M) XHh[(size_t)row * 256 + col] = f2h(acc[i][j][r]);
            }
        }
    }
}

// ------------------------------------------------------- a_src / a_dst ------
__global__ __launch_bounds__(256) void attn_coef(const unsigned short* __restrict__ xhh,
                                                 const float* __restrict__ attS,
                                                 const float* __restrict__ attD,
                                                 float* __restrict__ a_src,
                                                 float* __restrict__ a_dst,
                                                 int Nn) {
    int wid = threadIdx.x >> 6, lane = threadIdx.x & 63;
    int n = blockIdx.x * 4 + wid;
    if (n >= Nn) return;
    ushort4 xv = *(const ushort4*)&xhh[(size_t)n * HC + lane * 4];
    float x0 = h2f(xv.x), x1 = h2f(xv.y), x2 = h2f(xv.z), x3 = h2f(xv.w);
    float4 sv = *(const float4*)&attS[lane * 4];
    float4 dv = *(const float4*)&attD[lane * 4];
    float ps = x0 * sv.x + x1 * sv.y + x2 * sv.z + x3 * sv.w;
    float pd = x0 * dv.x + x1 * dv.y + x2 * dv.z + x3 * dv.w;
#pragma unroll
    for (int d = 1; d < 16; d <<= 1) {
        ps += __shfl_xor(ps, d, 64);
        pd += __shfl_xor(pd, d, 64);
    }
    if ((lane & 15) == 0) {
        a_src[n * 4 + (lane >> 4)] = ps;
        a_dst[n * 4 + (lane >> 4)] = pd;
    }
}

// ------------------------------------------------------------- CSR build ----
__global__ void hist_kernel(const int* __restrict__ dst, int* __restrict__ deg,
                            int* __restrict__ rank, int E) {
    int e = blockIdx.x * 256 + threadIdx.x;
    if (e < E) rank[e] = atomicAdd(&deg[dst[e]], 1);
}

// scan of PADDED degrees (each deg rounded up to x4)
__global__ __launch_bounds__(1024) void scan1(const int* __restrict__ deg,
                                              int* __restrict__ row_start,
                                              int* __restrict__ bsum, int n) {
    __shared__ int wsum[16];
    const int tid = threadIdx.x, lane = tid & 63, wid = tid >> 6;
    int i = blockIdx.x * 1024 + tid;
    int v = (i < n) ? ((deg[i] + 3) & ~3) : 0;
    int incl = v;
#pragma unroll
    for (int d = 1; d < 64; d <<= 1) {
        int t = __shfl_up(incl, d, 64);
        if (lane >= d) incl += t;
    }
    if (lane == 63) wsum[wid] = incl;
    __syncthreads();
    if (tid < 16) {
        int w = wsum[tid];
#pragma unroll
        for (int d = 1; d < 16; d <<= 1) {
            int t = __shfl_up(w, d, 16);
            if (tid >= d) w += t;
        }
        wsum[tid] = w;
    }
    __syncthreads();
    int waveoff = wid ? wsum[wid - 1] : 0;
    if (i < n) row_start[i] = waveoff + incl - v;
    if (tid == 1023) bsum[blockIdx.x] = waveoff + incl;
}

// fused scan2+scan3
__global__ __launch_bounds__(1024) void scan23(int* __restrict__ row_start,
                                               const int* __restrict__ bsum, int n, int nb) {
    __shared__ int pref[64];
    const int tid = threadIdx.x;
    if (tid < 64) {
        int v = (tid < nb) ? bsum[tid] : 0;
#pragma unroll
        for (int d = 1; d < 64; d <<= 1) {
            int t = __shfl_up(v, d, 64);
            if (tid >= d) v += t;
        }
        pref[tid] = v;
    }
    __syncthreads();
    int add = blockIdx.x ? pref[blockIdx.x - 1] : 0;
    int i = blockIdx.x * 1024 + tid;
    if (i < n) row_start[i] += add;
    if (i == n) row_start[n] = pref[nb - 1];
}

// ------------------------------------------------------------ scatter -------
// Single 8B combined record per edge -> ONE cacheline touch per edge.
__global__ void scatter_sw(const int* __restrict__ src, const int* __restrict__ dst,
                           const float* __restrict__ ew,
                           const int* __restrict__ row_start, const int* __restrict__ rank,
                           int2* __restrict__ sew, int E) {
    int e = blockIdx.x * 256 + threadIdx.x;
    if (e >= E) return;
    int pos = row_start[dst[e]] + rank[e];
    sew[pos] = make_int2(src[e], __float_as_int(ew[e]));
}

// --------------------------------------------------------------- p_pass -----
// SINGLE pass per node-wave: read combined records coalesced, gather a_src
// (L2-resident), p = exp(lrelu(alpha)) written as f32 (unnormalized), plus
// srcs and per-(node,head) esum. Pads get p=0, src=0. Normalization happens
// in gat_main (it has VALU headroom).
__global__ __launch_bounds__(256) void p_pass(
    const int* __restrict__ row_start, const int* __restrict__ deg,
    const int2* __restrict__ sew, const float* __restrict__ a_src,
    const float* __restrict__ a_dst, const float* __restrict__ cE,
    int* __restrict__ srcs, float* __restrict__ pq, float* __restrict__ esum,
    int Nn) {
    const int wid = threadIdx.x >> 6, lane = threadIdx.x & 63;
    const int n = blockIdx.x * 4 + wid;
    if (n >= Nn) return;
    const int rs = row_start[n];
    const int dn = deg[n];
    const int pd = (dn + 3) & ~3;
    const int slot0 = lane >> 2, h = lane & 3;
    const float adn = a_dst[n * 4 + h];
    const float ceh = cE[h];

    float psum = 0.f;
    for (int s = slot0; s < pd; s += 16) {
        int pos = rs + s;                       // rs is x4-aligned
        int2 r = sew[pos];
        float p = 0.f;
        int sv = 0;
        if (s < dn) {
            sv = r.x;
            float a = a_src[r.x * 4 + h] + adn + ceh * __int_as_float(r.y);
            a = fmaxf(a, 0.2f * a);             // leaky relu
            p = __expf(a);                      // no max-sub: |alpha| small
        }
        if (h == 0) srcs[pos] = sv;
        pq[(size_t)(pos >> 2) * 16 + h * 4 + (pos & 3)] = p;
        psum += p;
    }
    // reduce over slots (keeps h): lanes 0..3 hold heads 0..3
#pragma unroll
    for (int d = 4; d < 64; d <<= 1) psum += __shfl_xor(psum, d, 64);
    if (lane < 4) esum[(size_t)n * 4 + lane] = psum;
}

// ------------------------------------------------------------- main GAT -----
// One WAVE per node. Lane l owns channels 4l..4l+3 (head myh=l>>4).
// p is f32 unnormalized; rin = 1/esum[n][myh] loaded once; per edge:
// mul + cvt_pkrtz + 2 v_pk_fma_f16 (hidden under gather waits).
// Zero-copy period-4 pipeline (R10-proven). All chunks full.
__global__ __launch_bounds__(256) void gat_main(
    const unsigned short* __restrict__ xhh, const int* __restrict__ row_start,
    const int* __restrict__ srcs, const float* __restrict__ pqf,
    const float* __restrict__ esum, const float* __restrict__ bias,
    const float* __restrict__ gamma, const float* __restrict__ beta,
    unsigned short* __restrict__ yh, int Nn) {
    const int lane = threadIdx.x & 63, wid = threadIdx.x >> 6;
    const int n = blockIdx.x * 4 + wid;
    if (n >= Nn) return;
    const int myh = lane >> 4;
    const int rs = row_start[n], re = row_start[n + 1];
    const int rs4 = rs >> 2;
    const int G = (re - rs) >> 2;          // all chunks full

    const float rin = 1.f / (esum[(size_t)n * 4 + myh] + 1e-16f);

    f16x2 acc0 = {(_Float16)0, (_Float16)0};
    f16x2 acc1 = {(_Float16)0, (_Float16)0};

    int4   ms0 = {}, ms1 = {}, ms2 = {}, ms3 = {};
    float4 mp0 = {}, mp1 = {}, mp2 = {}, mp3 = {};
    f16x4 A0 = {}, A1 = {}, A2 = {}, A3 = {};
    f16x4 B0 = {}, B1 = {}, B2 = {}, B3 = {};

#define META(i, c_) do {                                                       \
    ms##i = *(const int4*)(srcs + ((size_t)(rs4 + (c_)) << 2));                \
    mp##i = *(const float4*)(pqf + ((size_t)(rs4 + (c_)) << 4) + (myh << 2));  \
} while (0)
#define ROW(D, sv_) do {                                                       \
    unsigned sb_ = __builtin_amdgcn_readfirstlane((unsigned)(sv_));            \
    const f16x4* rp_ = (const f16x4*)(xhh + (size_t)sb_ * HC);                 \
    D = rp_[lane];                                                             \
} while (0)
#define GATH(S, i) do {                                                        \
    ROW(S##0, ms##i.x); ROW(S##1, ms##i.y);                                    \
    ROW(S##2, ms##i.z); ROW(S##3, ms##i.w);                                    \
} while (0)
#define COMP(S, i) do {                                                        \
    edge_acc(mp##i.x, rin, S##0, acc0, acc1);                                  \
    edge_acc(mp##i.y, rin, S##1, acc0, acc1);                                  \
    edge_acc(mp##i.z, rin, S##2, acc0, acc1);                                  \
    edge_acc(mp##i.w, rin, S##3, acc0, acc1);                                  \
} while (0)

    if (G > 0) {
        META(0, 0); GATH(A, 0);
        if (G > 1) { META(1, 1); GATH(B, 1); }
        if (G > 2) META(2, 2);
        if (G > 3) META(3, 3);
        int c = 0;
        for (; c + 8 <= G; c += 4) {
            COMP(A, 0); GATH(A, 2); META(0, c + 4);
            COMP(B, 1); GATH(B, 3); META(1, c + 5);
            COMP(A, 2); GATH(A, 0); META(2, c + 6);
            COMP(B, 3); GATH(B, 1); META(3, c + 7);
        }
        int R = G - c;                      // 1..7
        COMP(A, 0);
        if (c + 2 < G) GATH(A, 2);
        if (c + 4 < G) META(0, c + 4);
        if (R > 1) {
            COMP(B, 1);
            if (c + 3 < G) GATH(B, 3);
            if (c + 5 < G) META(1, c + 5);
            if (R > 2) {
                COMP(A, 2);
                if (c + 4 < G) GATH(A, 0);
                if (c + 6 < G) META(2, c + 6);
                if (R > 3) {
                    COMP(B, 3);
                    if (c + 5 < G) GATH(B, 1);
                    if (R > 4) {
                        COMP(A, 0);
                        if (c + 6 < G) GATH(A, 2);
                        if (R > 5) {
                            COMP(B, 1);
                            if (R > 6) COMP(A, 2);
                        }
                    }
                }
            }
        }
    }
#undef META
#undef ROW
#undef GATH
#undef COMP

    // unpack (attn already normalized in-loop)
    float4 bv = *(const float4*)&bias[lane * 4];
    float v0 = (float)acc0[0] + bv.x;
    float v1 = (float)acc0[1] + bv.y;
    float v2 = (float)acc1[0] + bv.z;
    float v3 = (float)acc1[1] + bv.w;

    // LayerNorm over 256 channels (wave-wide reduce)
    float s1 = v0 + v1 + v2 + v3;
    float s2v = v0 * v0 + v1 * v1 + v2 * v2 + v3 * v3;
#pragma unroll
    for (int d = 1; d < 64; d <<= 1) {
        s1 += __shfl_xor(s1, d, 64);
        s2v += __shfl_xor(s2v, d, 64);
    }
    float mu = s1 * (1.f / 256.f);
    float var = s2v * (1.f / 256.f) - mu * mu;
    float rstd = rsqrtf(var + 1e-5f);
    float4 gv = *(const float4*)&gamma[lane * 4];
    float4 btv = *(const float4*)&beta[lane * 4];
    float y0 = fmaxf((v0 - mu) * rstd * gv.x + btv.x, 0.f);
    float y1 = fmaxf((v1 - mu) * rstd * gv.y + btv.y, 0.f);
    float y2 = fmaxf((v2 - mu) * rstd * gv.z + btv.z, 0.f);
    float y3 = fmaxf((v3 - mu) * rstd * gv.w + btv.w, 0.f);

    f16x4 yv;
    yv[0] = (_Float16)y0; yv[1] = (_Float16)y1;
    yv[2] = (_Float16)y2; yv[3] = (_Float16)y3;
    *(f16x4*)&yh[(size_t)n * HC + lane * 4] = yv;
}

// ------------------------------------------------------------ FC (MFMA) -----
// out[M,10] = y[M,256](f16) @ fcWh^T(f16,[16][256]) + fcb. 4 waves x 64 rows.
__global__ __launch_bounds__(256) void fc_gemm(const unsigned short* __restrict__ yh,
                                               const unsigned short* __restrict__ fcWh,
                                               const float* __restrict__ fcb,
                                               float* __restrict__ out, int M) {
    const int lane = threadIdx.x & 63, wid = threadIdx.x >> 6;
    const int rowbase = blockIdx.x * 256 + wid * 64;
    const int fr = lane & 15, kg = lane >> 4;
    f32x4 acc[4] = {};
#pragma unroll
    for (int k0 = 0; k0 < 256; k0 += 32) {
        f16x8 bfr = *(const f16x8*)&fcWh[fr * 256 + k0 + kg * 8];
#pragma unroll
        for (int i = 0; i < 4; ++i) {
            int row = rowbase + i * 16 + fr;
            f16x8 afr = {};
            if (row < M) afr = *(const f16x8*)&yh[(size_t)row * 256 + k0 + kg * 8];
            acc[i] = __builtin_amdgcn_mfma_f32_16x16x32_f16(afr, bfr, acc[i], 0, 0, 0);
        }
    }
    if (fr < NCLS) {
        float bb = fcb[fr];
#pragma unroll
        for (int i = 0; i < 4; ++i) {
#pragma unroll
            for (int r = 0; r < 4; ++r) {
                int row = rowbase + i * 16 + kg * 4 + r;
                if (row < M) out[(size_t)row * NCLS + fr] = acc[i][r] + bb;
            }
        }
    }
}

// ---------------------------------------------------------------- launch ----
extern "C" void kernel_launch(void* const* d_in, const int* in_sizes, int n_in,
                              void* d_out, int out_size, void* d_ws, size_t ws_size,
                              hipStream_t stream) {
    const float* x    = (const float*)d_in[0];
    const int*   ei   = (const int*)d_in[1];
    const float* ew   = (const float*)d_in[2];
    const float* W    = (const float*)d_in[3];
    const float* attS = (const float*)d_in[4];
    const float* attD = (const float*)d_in[5];
    const float* attE = (const float*)d_in[6];
    const float* We   = (const float*)d_in[7];
    const float* bias = (const float*)d_in[8];
    const float* gam  = (const float*)d_in[9];
    const float* bet  = (const float*)d_in[10];
    const float* fcW  = (const float*)d_in[11];
    const float* fcb  = (const float*)d_in[12];
    float* out = (float*)d_out;

    const int Nn = in_sizes[0] / HC;       // 50000
    const int E  = in_sizes[1] / 2;        // 800000
    const int* src = ei;
    const int* dst = ei + E;
    const int nb = (Nn + 1023) / 1024;     // 49
    const int EpMax = E + 4 * Nn;          // worst-case padded slots (x4 pad)

    char* ws = (char*)d_ws;
    size_t off = 0;
    auto alloc = [&](size_t bytes) { void* p = ws + off; off = (off + bytes + 255) & ~size_t(255); return p; };
    unsigned short* xhh  = (unsigned short*)alloc((size_t)Nn * HC * 2);
    unsigned short* yh   = (unsigned short*)alloc((size_t)Nn * HC * 2);
    unsigned short* wt   = (unsigned short*)alloc((size_t)HC * HC * 2);
    unsigned short* fcWh = (unsigned short*)alloc((size_t)16 * HC * 2);
    float* a_srcb    = (float*)alloc((size_t)Nn * 4 * 4);
    float* a_dstb    = (float*)alloc((size_t)Nn * 4 * 4);
    float* esum      = (float*)alloc((size_t)Nn * 4 * 4);
    float* cE        = (float*)alloc(256);
    int*   row_start = (int*)  alloc((size_t)(Nn + 1) * 4);
    int*   deg       = (int*)  alloc((size_t)Nn * 4);
    int*   bsum      = (int*)  alloc((size_t)nb * 4);
    int*   rank      = (int*)  alloc((size_t)E * 4);
    int2*  sew       = (int2*) alloc((size_t)EpMax * 8 + 256);   // {src, ew}
    int*   srcs      = (int*)  alloc((size_t)EpMax * 4 + 256);   // +slack
    float* pq        = (float*)alloc((size_t)EpMax * 16 + 1024); // [group][h][4] f32
    (void)ws_size;

    prep_kernel<<<273 + (Nn + 255) / 256, 256, 0, stream>>>(We, attE, cE, W, wt,
                                                            fcW, fcWh, deg, Nn);

    dim3 g((Nn + 127) / 128, 2);
    gemm_mfma<<<g, 256, 0, stream>>>(x, wt, xhh, Nn);

    attn_coef<<<(Nn + 3) / 4, 256, 0, stream>>>(xhh, attS, attD, a_srcb, a_dstb, Nn);
    hist_kernel<<<(E + 255) / 256, 256, 0, stream>>>(dst, deg, rank, E);
    scan1<<<nb, 1024, 0, stream>>>(deg, row_start, bsum, Nn);
    scan23<<<nb, 1024, 0, stream>>>(row_start, bsum, Nn, nb);
    scatter_sw<<<(E + 255) / 256, 256, 0, stream>>>(src, dst, ew, row_start, rank,
                                                    sew, E);
    p_pass<<<(Nn + 3) / 4, 256, 0, stream>>>(row_start, deg, sew,
                                             a_srcb, a_dstb, cE, srcs, pq, esum, Nn);
    gat_main<<<(Nn + 3) / 4, 256, 0, stream>>>(xhh, row_start, srcs, pq, esum,
                                               bias, gam, bet, yh, Nn);
    fc_gemm<<<(Nn + 255) / 256, 256, 0, stream>>>(yh, fcWh, fcb, out, Nn);
}

// Round 13
// 195.012 us; speedup vs baseline: 1.0247x; 1.0088x over previous
//
#include <hip/hip_runtime.h>
#include <hip/hip_bf16.h>

static constexpr int HEADS = 4;
static constexpr int HID   = 64;
static constexpr int HC    = 256;   // HEADS*HID
static constexpr int NCLS  = 10;

typedef short    bf16x8 __attribute__((ext_vector_type(8)));
typedef _Float16 f16x8  __attribute__((ext_vector_type(8)));
typedef _Float16 f16x4  __attribute__((ext_vector_type(4)));
typedef _Float16 f16x2  __attribute__((ext_vector_type(2)));
typedef float    f32x4  __attribute__((ext_vector_type(4)));

__device__ inline unsigned short f2bf(float f) {
    union { float f; unsigned u; } c; c.f = f;
    unsigned r = (c.u + 0x7fff + ((c.u >> 16) & 1)) >> 16;  // RNE
    return (unsigned short)r;
}
__device__ inline unsigned short f2h(float f) {
    _Float16 h = (_Float16)f; unsigned short u; __builtin_memcpy(&u, &h, 2); return u;
}
__device__ inline float h2f(unsigned short u) {
    _Float16 h; __builtin_memcpy(&h, &u, 2); return (float)h;
}

// p (unnormalized, f32) -> attn = p*rin, packed-f16 dup, 2x v_pk_fma_f16
__device__ inline void edge_acc(float p, float rin, f16x4 X, f16x2& a0, f16x2& a1) {
    float a = p * rin;
    auto pk = __builtin_amdgcn_cvt_pkrtz(a, a);   // __fp16 ext_vector(2)
    f16x2 ap;
    __builtin_memcpy(&ap, &pk, sizeof(ap));       // bit-cast to _Float16x2
    f16x2 lo = __builtin_shufflevector(X, X, 0, 1);
    f16x2 hi = __builtin_shufflevector(X, X, 2, 3);
    a0 = ap * lo + a0;   // v_pk_fma_f16
    a1 = ap * hi + a1;
}

// ------------------------------------------------------------------ prep ----
// b=0: cE; b=1..256: Wt; b=257..272: fcWh; b>=273: zero deg (fused memset)
__global__ void prep_kernel(const float* __restrict__ We, const float* __restrict__ attE,
                            float* __restrict__ cE, const float* __restrict__ W,
                            unsigned short* __restrict__ Wt, const float* __restrict__ fcW,
                            unsigned short* __restrict__ fcWh, int* __restrict__ deg,
                            int Nn) {
    int b = blockIdx.x, t = threadIdx.x;
    if (b == 0) {
        float p = We[t] * attE[t];
#pragma unroll
        for (int d = 32; d; d >>= 1) p += __shfl_xor(p, d, 64);
        if ((t & 63) == 0) cE[t >> 6] = p;
    } else if (b <= 256) {
        int k = b - 1;
        Wt[t * 256 + k] = f2bf(W[k * 256 + t]);
    } else if (b <= 272) {
        int j = b - 257;               // 0..15
        unsigned short v = 0;
        if (j < NCLS) v = f2h(fcW[t * NCLS + j]);
        fcWh[j * 256 + t] = v;
    } else {
        int i = (b - 273) * 256 + t;
        if (i < Nn) deg[i] = 0;
    }
}

// ------------------------------------------------------------ MFMA GEMM -----
// XHh[M,256](f16) = X[M,256](f32) @ Wt^T (bf16 MFMA).
// FUSED attn-coef epilogue: block (.,y) owns cols y*128..+127 = heads
// {2y, 2y+1}; wave (wr,wc) computes a_src/a_dst for its 64 rows x head
// (2y+wc) directly from f32 acc (4 fma + 16-lane shfl reduce per (i,r)).
__global__ __launch_bounds__(256) void gemm_mfma(const float* __restrict__ X,
                                                 const unsigned short* __restrict__ Bt,
                                                 unsigned short* __restrict__ XHh,
                                                 const float* __restrict__ attS,
                                                 const float* __restrict__ attD,
                                                 float* __restrict__ a_src,
                                                 float* __restrict__ a_dst, int M) {
    __shared__ alignas(16) unsigned short As[128][40];
    __shared__ alignas(16) unsigned short Bs[128][40];  // Bs[col][k]
    const int tid = threadIdx.x;
    const int lane = tid & 63, wid = tid >> 6;
    const int wr = wid >> 1, wc = wid & 1;
    const int bm = blockIdx.x * 128, bn = blockIdx.y * 128;
    const int fr = lane & 15, kg = lane >> 4;

    f32x4 acc[4][4] = {};

    for (int k0 = 0; k0 < 256; k0 += 32) {
        __syncthreads();
#pragma unroll
        for (int ss = 0; ss < 4; ++ss) {
            int idx = tid + (ss << 8);
            int row = idx >> 3, seg = idx & 7;
            int grow = bm + row;
            float4 av = make_float4(0.f, 0.f, 0.f, 0.f);
            if (grow < M) av = *(const float4*)&X[(size_t)grow * 256 + k0 + seg * 4];
            ushort4 ab = make_ushort4(f2bf(av.x), f2bf(av.y), f2bf(av.z), f2bf(av.w));
            *(ushort4*)&As[row][seg * 4] = ab;
        }
#pragma unroll
        for (int qq = 0; qq < 2; ++qq) {
            int q = tid + (qq << 8);
            int row = q >> 2, part = q & 3;
            const ushort4* bp = (const ushort4*)&Bt[(size_t)(bn + row) * 256 + k0 + part * 8];
            *(ushort4*)&Bs[row][part * 8]     = bp[0];
            *(ushort4*)&Bs[row][part * 8 + 4] = bp[1];
        }
        __syncthreads();

        bf16x8 af[4], bf[4];
#pragma unroll
        for (int i = 0; i < 4; ++i)
            af[i] = *(const bf16x8*)&As[wr * 64 + i * 16 + fr][kg * 8];
#pragma unroll
        for (int j = 0; j < 4; ++j)
            bf[j] = *(const bf16x8*)&Bs[wc * 64 + j * 16 + fr][kg * 8];
#pragma unroll
        for (int i = 0; i < 4; ++i)
#pragma unroll
            for (int j = 0; j < 4; ++j)
                acc[i][j] = __builtin_amdgcn_mfma_f32_16x16x32_bf16(af[i], bf[j], acc[i][j], 0, 0, 0);
    }

    // C/D layout: col = lane&15, row = (lane>>4)*4 + reg
#pragma unroll
    for (int i = 0; i < 4; ++i) {
#pragma unroll
        for (int j = 0; j < 4; ++j) {
            int col = bn + wc * 64 + j * 16 + fr;
#pragma unroll
            for (int r = 0; r < 4; ++r) {
                int row = bm + wr * 64 + i * 16 + kg * 4 + r;
                if (row < M) XHh[(size_t)row * 256 + col] = f2h(acc[i][j][r]);
            }
        }
    }

    // fused a_src/a_dst (head = blockIdx.y*2 + wc; this wave's 64 rows)
    const int head = blockIdx.y * 2 + wc;
    float sS[4], sD[4];
#pragma unroll
    for (int j = 0; j < 4; ++j) {
        sS[j] = attS[bn + wc * 64 + j * 16 + fr];
        sD[j] = attD[bn + wc * 64 + j * 16 + fr];
    }
#pragma unroll
    for (int i = 0; i < 4; ++i) {
#pragma unroll
        for (int r = 0; r < 4; ++r) {
            float ds = 0.f, dd = 0.f;
#pragma unroll
            for (int j = 0; j < 4; ++j) {
                float v = acc[i][j][r];
                ds = fmaf(v, sS[j], ds);
                dd = fmaf(v, sD[j], dd);
            }
#pragma unroll
            for (int d = 1; d < 16; d <<= 1) {
                ds += __shfl_xor(ds, d, 64);
                dd += __shfl_xor(dd, d, 64);
            }
            if (fr == 0) {
                int row = bm + wr * 64 + i * 16 + kg * 4 + r;
                if (row < M) {
                    a_src[row * 4 + head] = ds;
                    a_dst[row * 4 + head] = dd;
                }
            }
        }
    }
}

// ------------------------------------------------------------- CSR build ----
__global__ void hist_kernel(const int* __restrict__ dst, int* __restrict__ deg,
                            int* __restrict__ rank, int E) {
    int e = blockIdx.x * 256 + threadIdx.x;
    if (e < E) rank[e] = atomicAdd(&deg[dst[e]], 1);
}

// scan of PADDED degrees (each deg rounded up to x4)
__global__ __launch_bounds__(1024) void scan1(const int* __restrict__ deg,
                                              int* __restrict__ row_start,
                                              int* __restrict__ bsum, int n) {
    __shared__ int wsum[16];
    const int tid = threadIdx.x, lane = tid & 63, wid = tid >> 6;
    int i = blockIdx.x * 1024 + tid;
    int v = (i < n) ? ((deg[i] + 3) & ~3) : 0;
    int incl = v;
#pragma unroll
    for (int d = 1; d < 64; d <<= 1) {
        int t = __shfl_up(incl, d, 64);
        if (lane >= d) incl += t;
    }
    if (lane == 63) wsum[wid] = incl;
    __syncthreads();
    if (tid < 16) {
        int w = wsum[tid];
#pragma unroll
        for (int d = 1; d < 16; d <<= 1) {
            int t = __shfl_up(w, d, 16);
            if (tid >= d) w += t;
        }
        wsum[tid] = w;
    }
    __syncthreads();
    int waveoff = wid ? wsum[wid - 1] : 0;
    if (i < n) row_start[i] = waveoff + incl - v;
    if (tid == 1023) bsum[blockIdx.x] = waveoff + incl;
}

// fused scan2+scan3
__global__ __launch_bounds__(1024) void scan23(int* __restrict__ row_start,
                                               const int* __restrict__ bsum, int n, int nb) {
    __shared__ int pref[64];
    const int tid = threadIdx.x;
    if (tid < 64) {
        int v = (tid < nb) ? bsum[tid] : 0;
#pragma unroll
        for (int d = 1; d < 64; d <<= 1) {
            int t = __shfl_up(v, d, 64);
            if (tid >= d) v += t;
        }
        pref[tid] = v;
    }
    __syncthreads();
    int add = blockIdx.x ? pref[blockIdx.x - 1] : 0;
    int i = blockIdx.x * 1024 + tid;
    if (i < n) row_start[i] += add;
    if (i == n) row_start[n] = pref[nb - 1];
}

// ------------------------------------------------------------ scatter -------
// Single 8B combined record per edge -> ONE cacheline touch per edge.
__global__ void scatter_sw(const int* __restrict__ src, const int* __restrict__ dst,
                           const float* __restrict__ ew,
                           const int* __restrict__ row_start, const int* __restrict__ rank,
                           int2* __restrict__ sew, int E) {
    int e = blockIdx.x * 256 + threadIdx.x;
    if (e >= E) return;
    int pos = row_start[dst[e]] + rank[e];
    sew[pos] = make_int2(src[e], __float_as_int(ew[e]));
}

// --------------------------------------------------------------- p_pass -----
// SINGLE pass per node-wave: read combined records coalesced, gather a_src
// (L2-resident), p = exp(lrelu(alpha)) written as f32 (unnormalized), plus
// srcs and per-(node,head) esum. Pads get p=0, src=0.
__global__ __launch_bounds__(256) void p_pass(
    const int* __restrict__ row_start, const int* __restrict__ deg,
    const int2* __restrict__ sew, const float* __restrict__ a_src,
    const float* __restrict__ a_dst, const float* __restrict__ cE,
    int* __restrict__ srcs, float* __restrict__ pq, float* __restrict__ esum,
    int Nn) {
    const int wid = threadIdx.x >> 6, lane = threadIdx.x & 63;
    const int n = blockIdx.x * 4 + wid;
    if (n >= Nn) return;
    const int rs = row_start[n];
    const int dn = deg[n];
    const int pd = (dn + 3) & ~3;
    const int slot0 = lane >> 2, h = lane & 3;
    const float adn = a_dst[n * 4 + h];
    const float ceh = cE[h];

    float psum = 0.f;
    for (int s = slot0; s < pd; s += 16) {
        int pos = rs + s;                       // rs is x4-aligned
        int2 r = sew[pos];
        float p = 0.f;
        int sv = 0;
        if (s < dn) {
            sv = r.x;
            float a = a_src[r.x * 4 + h] + adn + ceh * __int_as_float(r.y);
            a = fmaxf(a, 0.2f * a);             // leaky relu
            p = __expf(a);                      // no max-sub: |alpha| small
        }
        if (h == 0) srcs[pos] = sv;
        pq[(size_t)(pos >> 2) * 16 + h * 4 + (pos & 3)] = p;
        psum += p;
    }
    // reduce over slots (keeps h): lanes 0..3 hold heads 0..3
#pragma unroll
    for (int d = 4; d < 64; d <<= 1) psum += __shfl_xor(psum, d, 64);
    if (lane < 4) esum[(size_t)n * 4 + lane] = psum;
}

// ------------------------------------------------------------- main GAT -----
// One WAVE per node. Lane l owns channels 4l..4l+3 (head myh=l>>4).
// p is f32 unnormalized; rin = 1/esum[n][myh] loaded once; per edge:
// mul + cvt_pkrtz + 2 v_pk_fma_f16 (hidden under gather waits).
// Zero-copy period-4 pipeline (R10-proven). All chunks full.
__global__ __launch_bounds__(256) void gat_main(
    const unsigned short* __restrict__ xhh, const int* __restrict__ row_start,
    const int* __restrict__ srcs, const float* __restrict__ pqf,
    const float* __restrict__ esum, const float* __restrict__ bias,
    const float* __restrict__ gamma, const float* __restrict__ beta,
    unsigned short* __restrict__ yh, int Nn) {
    const int lane = threadIdx.x & 63, wid = threadIdx.x >> 6;
    const int n = blockIdx.x * 4 + wid;
    if (n >= Nn) return;
    const int myh = lane >> 4;
    const int rs = row_start[n], re = row_start[n + 1];
    const int rs4 = rs >> 2;
    const int G = (re - rs) >> 2;          // all chunks full

    const float rin = 1.f / (esum[(size_t)n * 4 + myh] + 1e-16f);

    f16x2 acc0 = {(_Float16)0, (_Float16)0};
    f16x2 acc1 = {(_Float16)0, (_Float16)0};

    int4   ms0 = {}, ms1 = {}, ms2 = {}, ms3 = {};
    float4 mp0 = {}, mp1 = {}, mp2 = {}, mp3 = {};
    f16x4 A0 = {}, A1 = {}, A2 = {}, A3 = {};
    f16x4 B0 = {}, B1 = {}, B2 = {}, B3 = {};

#define META(i, c_) do {                                                       \
    ms##i = *(const int4*)(srcs + ((size_t)(rs4 + (c_)) << 2));                \
    mp##i = *(const float4*)(pqf + ((size_t)(rs4 + (c_)) << 4) + (myh << 2));  \
} while (0)
#define ROW(D, sv_) do {                                                       \
    unsigned sb_ = __builtin_amdgcn_readfirstlane((unsigned)(sv_));            \
    const f16x4* rp_ = (const f16x4*)(xhh + (size_t)sb_ * HC);                 \
    D = rp_[lane];                                                             \
} while (0)
#define GATH(S, i) do {                                                        \
    ROW(S##0, ms##i.x); ROW(S##1, ms##i.y);                                    \
    ROW(S##2, ms##i.z); ROW(S##3, ms##i.w);                                    \
} while (0)
#define COMP(S, i) do {                                                        \
    edge_acc(mp##i.x, rin, S##0, acc0, acc1);                                  \
    edge_acc(mp##i.y, rin, S##1, acc0, acc1);                                  \
    edge_acc(mp##i.z, rin, S##2, acc0, acc1);                                  \
    edge_acc(mp##i.w, rin, S##3, acc0, acc1);                                  \
} while (0)

    if (G > 0) {
        META(0, 0); GATH(A, 0);
        if (G > 1) { META(1, 1); GATH(B, 1); }
        if (G > 2) META(2, 2);
        if (G > 3) META(3, 3);
        int c = 0;
        for (; c + 8 <= G; c += 4) {
            COMP(A, 0); GATH(A, 2); META(0, c + 4);
            COMP(B, 1); GATH(B, 3); META(1, c + 5);
            COMP(A, 2); GATH(A, 0); META(2, c + 6);
            COMP(B, 3); GATH(B, 1); META(3, c + 7);
        }
        int R = G - c;                      // 1..7
        COMP(A, 0);
        if (c + 2 < G) GATH(A, 2);
        if (c + 4 < G) META(0, c + 4);
        if (R > 1) {
            COMP(B, 1);
            if (c + 3 < G) GATH(B, 3);
            if (c + 5 < G) META(1, c + 5);
            if (R > 2) {
                COMP(A, 2);
                if (c + 4 < G) GATH(A, 0);
                if (c + 6 < G) META(2, c + 6);
                if (R > 3) {
                    COMP(B, 3);
                    if (c + 5 < G) GATH(B, 1);
                    if (R > 4) {
                        COMP(A, 0);
                        if (c + 6 < G) GATH(A, 2);
                        if (R > 5) {
                            COMP(B, 1);
                            if (R > 6) COMP(A, 2);
                        }
                    }
                }
            }
        }
    }
#undef META
#undef ROW
#undef GATH
#undef COMP

    // unpack (attn already normalized in-loop)
    float4 bv = *(const float4*)&bias[lane * 4];
    float v0 = (float)acc0[0] + bv.x;
    float v1 = (float)acc0[1] + bv.y;
    float v2 = (float)acc1[0] + bv.z;
    float v3 = (float)acc1[1] + bv.w;

    // LayerNorm over 256 channels (wave-wide reduce)
    float s1 = v0 + v1 + v2 + v3;
    float s2v = v0 * v0 + v1 * v1 + v2 * v2 + v3 * v3;
#pragma unroll
    for (int d = 1; d < 64; d <<= 1) {
        s1 += __shfl_xor(s1, d, 64);
        s2v += __shfl_xor(s2v, d, 64);
    }
    float mu = s1 * (1.f / 256.f);
    float var = s2v * (1.f / 256.f) - mu * mu;
    float rstd = rsqrtf(var + 1e-5f);
    float4 gv = *(const float4*)&gamma[lane * 4];
    float4 btv = *(const float4*)&beta[lane * 4];
    float y0 = fmaxf((v0 - mu) * rstd * gv.x + btv.x, 0.f);
    float y1 = fmaxf((v1 - mu) * rstd * gv.y + btv.y, 0.f);
    float y2 = fmaxf((v2 - mu) * rstd * gv.z + btv.z, 0.f);
    float y3 = fmaxf((v3 - mu) * rstd * gv.w + btv.w, 0.f);

    f16x4 yv;
    yv[0] = (_Float16)y0; yv[1] = (_Float16)y1;
    yv[2] = (_Float16)y2; yv[3] = (_Float16)y3;
    *(f16x4*)&yh[(size_t)n * HC + lane * 4] = yv;
}

// ------------------------------------------------------------ FC (MFMA) -----
// out[M,10] = y[M,256](f16) @ fcWh^T(f16,[16][256]) + fcb. 4 waves x 64 rows.
__global__ __launch_bounds__(256) void fc_gemm(const unsigned short* __restrict__ yh,
                                               const unsigned short* __restrict__ fcWh,
                                               const float* __restrict__ fcb,
                                               float* __restrict__ out, int M) {
    const int lane = threadIdx.x & 63, wid = threadIdx.x >> 6;
    const int rowbase = blockIdx.x * 256 + wid * 64;
    const int fr = lane & 15, kg = lane >> 4;
    f32x4 acc[4] = {};
#pragma unroll
    for (int k0 = 0; k0 < 256; k0 += 32) {
        f16x8 bfr = *(const f16x8*)&fcWh[fr * 256 + k0 + kg * 8];
#pragma unroll
        for (int i = 0; i < 4; ++i) {
            int row = rowbase + i * 16 + fr;
            f16x8 afr = {};
            if (row < M) afr = *(const f16x8*)&yh[(size_t)row * 256 + k0 + kg * 8];
            acc[i] = __builtin_amdgcn_mfma_f32_16x16x32_f16(afr, bfr, acc[i], 0, 0, 0);
        }
    }
    if (fr < NCLS) {
        float bb = fcb[fr];
#pragma unroll
        for (int i = 0; i < 4; ++i) {
#pragma unroll
            for (int r = 0; r < 4; ++r) {
                int row = rowbase + i * 16 + kg * 4 + r;
                if (row < M) out[(size_t)row * NCLS + fr] = acc[i][r] + bb;
            }
        }
    }
}

// ---------------------------------------------------------------- launch ----
extern "C" void kernel_launch(void* const* d_in, const int* in_sizes, int n_in,
                              void* d_out, int out_size, void* d_ws, size_t ws_size,
                              hipStream_t stream) {
    const float* x    = (const float*)d_in[0];
    const int*   ei   = (const int*)d_in[1];
    const float* ew   = (const float*)d_in[2];
    const float* W    = (const float*)d_in[3];
    const float* attS = (const float*)d_in[4];
    const float* attD = (const float*)d_in[5];
    const float* attE = (const float*)d_in[6];
    const float* We   = (const float*)d_in[7];
    const float* bias = (const float*)d_in[8];
    const float* gam  = (const float*)d_in[9];
    const float* bet  = (const float*)d_in[10];
    const float* fcW  = (const float*)d_in[11];
    const float* fcb  = (const float*)d_in[12];
    float* out = (float*)d_out;

    const int Nn = in_sizes[0] / HC;       // 50000
    const int E  = in_sizes[1] / 2;        // 800000
    const int* src = ei;
    const int* dst = ei + E;
    const int nb = (Nn + 1023) / 1024;     // 49
    const int EpMax = E + 4 * Nn;          // worst-case padded slots (x4 pad)

    char* ws = (char*)d_ws;
    size_t off = 0;
    auto alloc = [&](size_t bytes) { void* p = ws + off; off = (off + bytes + 255) & ~size_t(255); return p; };
    unsigned short* xhh  = (unsigned short*)alloc((size_t)Nn * HC * 2);
    unsigned short* yh   = (unsigned short*)alloc((size_t)Nn * HC * 2);
    unsigned short* wt   = (unsigned short*)alloc((size_t)HC * HC * 2);
    unsigned short* fcWh = (unsigned short*)alloc((size_t)16 * HC * 2);
    float* a_srcb    = (float*)alloc((size_t)Nn * 4 * 4);
    float* a_dstb    = (float*)alloc((size_t)Nn * 4 * 4);
    float* esum      = (float*)alloc((size_t)Nn * 4 * 4);
    float* cE        = (float*)alloc(256);
    int*   row_start = (int*)  alloc((size_t)(Nn + 1) * 4);
    int*   deg       = (int*)  alloc((size_t)Nn * 4);
    int*   bsum      = (int*)  alloc((size_t)nb * 4);
    int*   rank      = (int*)  alloc((size_t)E * 4);
    int2*  sew       = (int2*) alloc((size_t)EpMax * 8 + 256);   // {src, ew}
    int*   srcs      = (int*)  alloc((size_t)EpMax * 4 + 256);   // +slack
    float* pq        = (float*)alloc((size_t)EpMax * 16 + 1024); // [group][h][4] f32
    (void)ws_size;

    prep_kernel<<<273 + (Nn + 255) / 256, 256, 0, stream>>>(We, attE, cE, W, wt,
                                                            fcW, fcWh, deg, Nn);

    dim3 g((Nn + 127) / 128, 2);
    gemm_mfma<<<g, 256, 0, stream>>>(x, wt, xhh, attS, attD, a_srcb, a_dstb, Nn);

    hist_kernel<<<(E + 255) / 256, 256, 0, stream>>>(dst, deg, rank, E);
    scan1<<<nb, 1024, 0, stream>>>(deg, row_start, bsum, Nn);
    scan23<<<nb, 1024, 0, stream>>>(row_start, bsum, Nn, nb);
    scatter_sw<<<(E + 255) / 256, 256, 0, stream>>>(src, dst, ew, row_start, rank,
                                                    sew, E);
    p_pass<<<(Nn + 3) / 4, 256, 0, stream>>>(row_start, deg, sew,
                                             a_srcb, a_dstb, cE, srcs, pq, esum, Nn);
    gat_main<<<(Nn + 3) / 4, 256, 0, stream>>>(xhh, row_start, srcs, pq, esum,
                                               bias, gam, bet, yh, Nn);
    fc_gemm<<<(Nn + 255) / 256, 256, 0, stream>>>(yh, fcWh, fcb, out, Nn);
}